// Round 1
// baseline (1296.612 us; speedup 1.0000x reference)
//
#include <hip/hip_runtime.h>

#define NN 200000
#define NE 6400000
#define FIN 256
#define HID 16
#define NC 40

__global__ __launch_bounds__(256) void k_init_deg(float* __restrict__ deg) {
    int i = blockIdx.x * 256 + threadIdx.x;
    if (i < NN) deg[i] = 1.0f;  // self-loop weight
}

__global__ __launch_bounds__(256) void k_deg_acc(const int* __restrict__ dst,
                                                 const float* __restrict__ w,
                                                 float* __restrict__ deg) {
    int e = blockIdx.x * 256 + threadIdx.x;
    if (e < NE) atomicAdd(&deg[dst[e]], w[e]);
}

__global__ __launch_bounds__(256) void k_dinv(float* __restrict__ deg) {
    int i = blockIdx.x * 256 + threadIdx.x;
    if (i < NN) {
        float d = deg[i];
        deg[i] = (d > 0.0f) ? rsqrtf(d) : 0.0f;
    }
}

__global__ __launch_bounds__(256) void k_norm(const int* __restrict__ src,
                                              const int* __restrict__ dst,
                                              const float* __restrict__ w,
                                              const float* __restrict__ dinv,
                                              float* __restrict__ norm) {
    int e = blockIdx.x * 256 + threadIdx.x;
    if (e < NE) norm[e] = dinv[src[e]] * w[e] * dinv[dst[e]];
}

// h = x @ W1 ; agg1 = h * dinv^2 (self-loop contribution pre-seeded)
// thread-per-row; W1 indices are wave-uniform -> scalar loads through K$.
__global__ __launch_bounds__(256) void k_gemm1(const float* __restrict__ x,
                                               const float* __restrict__ W1,
                                               const float* __restrict__ dinv,
                                               float* __restrict__ h,
                                               float* __restrict__ agg1) {
    int row = blockIdx.x * 256 + threadIdx.x;
    if (row >= NN) return;
    float acc[HID];
#pragma unroll
    for (int f = 0; f < HID; ++f) acc[f] = 0.0f;
    const float4* x4 = reinterpret_cast<const float4*>(x + (size_t)row * FIN);
    for (int kk = 0; kk < FIN / 4; ++kk) {
        float4 xv = x4[kk];
#pragma unroll
        for (int j = 0; j < 4; ++j) {
            float xs = (j == 0) ? xv.x : (j == 1) ? xv.y : (j == 2) ? xv.z : xv.w;
            int k = kk * 4 + j;
#pragma unroll
            for (int f = 0; f < HID; ++f)
                acc[f] = fmaf(xs, W1[k * HID + f], acc[f]);
        }
    }
    float di = dinv[row];
    float sl = di * di;
    float4* hp = reinterpret_cast<float4*>(h + (size_t)row * HID);
    float4* ap = reinterpret_cast<float4*>(agg1 + (size_t)row * HID);
#pragma unroll
    for (int q = 0; q < HID / 4; ++q) {
        float4 hv = make_float4(acc[q*4], acc[q*4+1], acc[q*4+2], acc[q*4+3]);
        hp[q] = hv;
        ap[q] = make_float4(hv.x * sl, hv.y * sl, hv.z * sl, hv.w * sl);
    }
}

// one thread per (edge, feature): agg[dst][f] += h[src][f] * norm[e]
__global__ __launch_bounds__(256) void k_pass(const int* __restrict__ src,
                                              const int* __restrict__ dst,
                                              const float* __restrict__ norm,
                                              const float* __restrict__ hin,
                                              float* __restrict__ agg) {
    long long t = (long long)blockIdx.x * 256 + threadIdx.x;
    if (t >= (long long)NE * HID) return;
    int e = (int)(t >> 4);
    int f = (int)(t & (HID - 1));
    float nv = norm[e];
    int s = src[e];
    int d = dst[e];
    atomicAdd(&agg[(size_t)d * HID + f], hin[(size_t)s * HID + f] * nv);
}

// h1 = relu(agg1 + b1) in place ; agg2 = h1 * dinv^2 (layer-2 self-loop seed)
__global__ __launch_bounds__(256) void k_relu(float* __restrict__ agg1,
                                              const float* __restrict__ b1,
                                              const float* __restrict__ dinv,
                                              float* __restrict__ agg2) {
    int t = blockIdx.x * 256 + threadIdx.x;
    if (t < NN * HID) {
        int i = t >> 4;
        int f = t & (HID - 1);
        float v = agg1[t] + b1[f];
        v = (v > 0.0f) ? v : 0.0f;
        agg1[t] = v;
        float di = dinv[i];
        agg2[t] = v * di * di;
    }
}

// out = agg2 @ W2 + b2   (aggregate-first reordering of layer 2)
__global__ __launch_bounds__(256) void k_gemm2(const float* __restrict__ agg2,
                                               const float* __restrict__ W2,
                                               const float* __restrict__ b2,
                                               float* __restrict__ out) {
    int row = blockIdx.x * 256 + threadIdx.x;
    if (row >= NN) return;
    float a[HID];
    const float4* ap = reinterpret_cast<const float4*>(agg2 + (size_t)row * HID);
#pragma unroll
    for (int q = 0; q < HID / 4; ++q) {
        float4 v = ap[q];
        a[q*4] = v.x; a[q*4+1] = v.y; a[q*4+2] = v.z; a[q*4+3] = v.w;
    }
    float acc[NC];
#pragma unroll
    for (int c = 0; c < NC; ++c) acc[c] = b2[c];
#pragma unroll
    for (int k = 0; k < HID; ++k) {
#pragma unroll
        for (int c = 0; c < NC; ++c)
            acc[c] = fmaf(a[k], W2[k * NC + c], acc[c]);
    }
    float4* op = reinterpret_cast<float4*>(out + (size_t)row * NC);
#pragma unroll
    for (int q = 0; q < NC / 4; ++q)
        op[q] = make_float4(acc[q*4], acc[q*4+1], acc[q*4+2], acc[q*4+3]);
}

extern "C" void kernel_launch(void* const* d_in, const int* in_sizes, int n_in,
                              void* d_out, int out_size, void* d_ws, size_t ws_size,
                              hipStream_t stream) {
    const float* x  = (const float*)d_in[0];
    const int*   ei = (const int*)d_in[1];   // [2, E] int32 (JAX demotes int64 w/o x64)
    const float* w  = (const float*)d_in[2];
    const float* W1 = (const float*)d_in[3];
    const float* b1 = (const float*)d_in[4];
    const float* W2 = (const float*)d_in[5];
    const float* b2 = (const float*)d_in[6];
    float* out = (float*)d_out;

    const int* src = ei;        // edge_index[0]
    const int* dst = ei + NE;   // edge_index[1]

    float* ws   = (float*)d_ws;
    float* dinv = ws;                 // NN floats (deg -> dinv in place)
    float* norm = ws + 200000;        // NE floats
    float* h    = ws + 6600000;       // NN*HID
    float* agg1 = ws + 9800000;       // NN*HID
    float* agg2 = h;                  // h is dead after pass1 -> reuse

    const int BN  = (NN + 255) / 256;                           // 782
    const int BE  = (NE + 255) / 256;                           // 25000
    const int BEF = (int)(((long long)NE * HID + 255) / 256);   // 400000
    const int BNF = (NN * HID + 255) / 256;                     // 12500

    k_init_deg<<<BN, 256, 0, stream>>>(dinv);
    k_deg_acc<<<BE, 256, 0, stream>>>(dst, w, dinv);
    k_dinv<<<BN, 256, 0, stream>>>(dinv);
    k_norm<<<BE, 256, 0, stream>>>(src, dst, w, dinv, norm);
    k_gemm1<<<BN, 256, 0, stream>>>(x, W1, dinv, h, agg1);
    k_pass<<<BEF, 256, 0, stream>>>(src, dst, norm, h, agg1);
    k_relu<<<BNF, 256, 0, stream>>>(agg1, b1, dinv, agg2);
    k_pass<<<BEF, 256, 0, stream>>>(src, dst, norm, agg1, agg2);
    k_gemm2<<<BN, 256, 0, stream>>>(agg2, W2, b2, out);
}

// Round 2
// 1243.502 us; speedup vs baseline: 1.0427x; 1.0427x over previous
//
#include <hip/hip_runtime.h>

#define NN 200000
#define NE 6400000
#define FIN 256
#define HID 16
#define NC 40
#define NBLK_SCAN 782   // ceil(NN/256)

// ---------------- preprocessing: degree + histogram ----------------

__global__ __launch_bounds__(256) void k_init(float* __restrict__ deg,
                                              int* __restrict__ cnt) {
    int i = blockIdx.x * 256 + threadIdx.x;
    if (i < NN) { deg[i] = 1.0f; cnt[i] = 0; }   // self-loop weight 1
}

__global__ __launch_bounds__(256) void k_hist(const int* __restrict__ dst,
                                              const float* __restrict__ w,
                                              float* __restrict__ deg,
                                              int* __restrict__ cnt) {
    int e = blockIdx.x * 256 + threadIdx.x;
    if (e < NE) {
        int d = dst[e];
        atomicAdd(&deg[d], w[e]);
        atomicAdd(&cnt[d], 1);
    }
}

__global__ __launch_bounds__(256) void k_dinv(float* __restrict__ deg) {
    int i = blockIdx.x * 256 + threadIdx.x;
    if (i < NN) {
        float d = deg[i];
        deg[i] = (d > 0.0f) ? rsqrtf(d) : 0.0f;
    }
}

// ---------------- 3-kernel exclusive scan of cnt -> row_start ----------------

__global__ __launch_bounds__(256) void k_scan1(const int* __restrict__ cnt,
                                               int* __restrict__ row_start,
                                               int* __restrict__ partial) {
    __shared__ int sm[256];
    int t = threadIdx.x;
    int i = blockIdx.x * 256 + t;
    int v = (i < NN) ? cnt[i] : 0;
    sm[t] = v;
    __syncthreads();
    for (int off = 1; off < 256; off <<= 1) {
        int x = (t >= off) ? sm[t - off] : 0;
        __syncthreads();
        sm[t] += x;
        __syncthreads();
    }
    if (i < NN) row_start[i] = sm[t] - v;      // exclusive within block
    if (t == 255) partial[blockIdx.x] = sm[255];
}

__global__ __launch_bounds__(1024) void k_scan2(int* __restrict__ partial) {
    __shared__ int sm[1024];
    int t = threadIdx.x;
    int v = (t < NBLK_SCAN) ? partial[t] : 0;
    sm[t] = v;
    __syncthreads();
    for (int off = 1; off < 1024; off <<= 1) {
        int x = (t >= off) ? sm[t - off] : 0;
        __syncthreads();
        sm[t] += x;
        __syncthreads();
    }
    if (t < NBLK_SCAN) partial[t] = sm[t] - v;  // exclusive block offsets
}

__global__ __launch_bounds__(256) void k_scan3(int* __restrict__ row_start,
                                               const int* __restrict__ partial,
                                               int* __restrict__ cnt) {
    int i = blockIdx.x * 256 + threadIdx.x;
    if (i < NN) {
        row_start[i] += partial[i >> 8];
        cnt[i] = 0;                              // reuse as fill cursor
    }
    if (i == 0) row_start[NN] = NE;
}

// ---------------- scatter edges into CSR (fuses norm computation) ----------------

__global__ __launch_bounds__(256) void k_scatter(const int* __restrict__ src,
                                                 const int* __restrict__ dst,
                                                 const float* __restrict__ w,
                                                 const float* __restrict__ dinv,
                                                 const int* __restrict__ row_start,
                                                 int* __restrict__ cnt,
                                                 int2* __restrict__ edges) {
    int e = blockIdx.x * 256 + threadIdx.x;
    if (e < NE) {
        int d = dst[e];
        int s = src[e];
        float nv = dinv[s] * w[e] * dinv[d];
        int pos = row_start[d] + atomicAdd(&cnt[d], 1);
        edges[pos] = make_int2(s, __float_as_int(nv));
    }
}

// ---------------- h = x @ W1 ----------------

__global__ __launch_bounds__(256) void k_gemm1(const float* __restrict__ x,
                                               const float* __restrict__ W1,
                                               float* __restrict__ h) {
    int row = blockIdx.x * 256 + threadIdx.x;
    if (row >= NN) return;
    float acc[HID];
#pragma unroll
    for (int f = 0; f < HID; ++f) acc[f] = 0.0f;
    const float4* x4 = reinterpret_cast<const float4*>(x + (size_t)row * FIN);
    for (int kk = 0; kk < FIN / 4; ++kk) {
        float4 xv = x4[kk];
#pragma unroll
        for (int j = 0; j < 4; ++j) {
            float xs = (j == 0) ? xv.x : (j == 1) ? xv.y : (j == 2) ? xv.z : xv.w;
            int k = kk * 4 + j;
#pragma unroll
            for (int f = 0; f < HID; ++f)
                acc[f] = fmaf(xs, W1[k * HID + f], acc[f]);
        }
    }
    float4* hp = reinterpret_cast<float4*>(h + (size_t)row * HID);
#pragma unroll
    for (int q = 0; q < HID / 4; ++q)
        hp[q] = make_float4(acc[q*4], acc[q*4+1], acc[q*4+2], acc[q*4+3]);
}

// ---------------- gather layer 1: h1 = relu(Ahat h + b1) ----------------
// 4 lanes per node; 16-feature accumulator in registers; butterfly reduce.

__global__ __launch_bounds__(256) void k_gather1(const int* __restrict__ row_start,
                                                 const int2* __restrict__ edges,
                                                 const float* __restrict__ h,
                                                 const float* __restrict__ dinv,
                                                 const float* __restrict__ b1,
                                                 float* __restrict__ h1) {
    int t = blockIdx.x * 256 + threadIdx.x;   // grid exact: 4*NN threads
    int i = t >> 2;
    int sub = t & 3;
    int beg = row_start[i];
    int end = row_start[i + 1];
    float4 a0 = make_float4(0.f,0.f,0.f,0.f), a1 = a0, a2 = a0, a3 = a0;
    if (sub == 0) {  // self-loop: dinv[i]^2 * h[i]
        float di = dinv[i];
        float sl = di * di;
        const float4* hp = reinterpret_cast<const float4*>(h + (size_t)i * HID);
        float4 v0 = hp[0], v1 = hp[1], v2 = hp[2], v3 = hp[3];
        a0 = make_float4(v0.x*sl, v0.y*sl, v0.z*sl, v0.w*sl);
        a1 = make_float4(v1.x*sl, v1.y*sl, v1.z*sl, v1.w*sl);
        a2 = make_float4(v2.x*sl, v2.y*sl, v2.z*sl, v2.w*sl);
        a3 = make_float4(v3.x*sl, v3.y*sl, v3.z*sl, v3.w*sl);
    }
    for (int p = beg + sub; p < end; p += 4) {
        int2 ev = edges[p];
        float nv = __int_as_float(ev.y);
        const float4* hp = reinterpret_cast<const float4*>(h + (size_t)ev.x * HID);
        float4 v0 = hp[0], v1 = hp[1], v2 = hp[2], v3 = hp[3];
        a0.x = fmaf(v0.x, nv, a0.x); a0.y = fmaf(v0.y, nv, a0.y);
        a0.z = fmaf(v0.z, nv, a0.z); a0.w = fmaf(v0.w, nv, a0.w);
        a1.x = fmaf(v1.x, nv, a1.x); a1.y = fmaf(v1.y, nv, a1.y);
        a1.z = fmaf(v1.z, nv, a1.z); a1.w = fmaf(v1.w, nv, a1.w);
        a2.x = fmaf(v2.x, nv, a2.x); a2.y = fmaf(v2.y, nv, a2.y);
        a2.z = fmaf(v2.z, nv, a2.z); a2.w = fmaf(v2.w, nv, a2.w);
        a3.x = fmaf(v3.x, nv, a3.x); a3.y = fmaf(v3.y, nv, a3.y);
        a3.z = fmaf(v3.z, nv, a3.z); a3.w = fmaf(v3.w, nv, a3.w);
    }
#pragma unroll
    for (int m = 1; m <= 2; m <<= 1) {
        a0.x += __shfl_xor(a0.x, m); a0.y += __shfl_xor(a0.y, m);
        a0.z += __shfl_xor(a0.z, m); a0.w += __shfl_xor(a0.w, m);
        a1.x += __shfl_xor(a1.x, m); a1.y += __shfl_xor(a1.y, m);
        a1.z += __shfl_xor(a1.z, m); a1.w += __shfl_xor(a1.w, m);
        a2.x += __shfl_xor(a2.x, m); a2.y += __shfl_xor(a2.y, m);
        a2.z += __shfl_xor(a2.z, m); a2.w += __shfl_xor(a2.w, m);
        a3.x += __shfl_xor(a3.x, m); a3.y += __shfl_xor(a3.y, m);
        a3.z += __shfl_xor(a3.z, m); a3.w += __shfl_xor(a3.w, m);
    }
    // lane `sub` writes quadrant `sub` with bias+relu
    float4 q = (sub == 0) ? a0 : (sub == 1) ? a1 : (sub == 2) ? a2 : a3;
    float4 bb = reinterpret_cast<const float4*>(b1)[sub];
    q.x = fmaxf(q.x + bb.x, 0.f);
    q.y = fmaxf(q.y + bb.y, 0.f);
    q.z = fmaxf(q.z + bb.z, 0.f);
    q.w = fmaxf(q.w + bb.w, 0.f);
    reinterpret_cast<float4*>(h1 + (size_t)i * HID)[sub] = q;
}

// ---------------- gather layer 2 fused with GEMM2: out = (Ahat h1) @ W2 + b2 ----------------

__global__ __launch_bounds__(256) void k_gather2(const int* __restrict__ row_start,
                                                 const int2* __restrict__ edges,
                                                 const float* __restrict__ h1,
                                                 const float* __restrict__ dinv,
                                                 const float* __restrict__ W2,
                                                 const float* __restrict__ b2,
                                                 float* __restrict__ out) {
    __shared__ float sW2[HID * NC];
    __shared__ float sb2[NC];
    {
        int t = threadIdx.x;
        for (int j = t; j < HID * NC; j += 256) sW2[j] = W2[j];
        if (t < NC) sb2[t] = b2[t];
    }
    __syncthreads();
    int t = blockIdx.x * 256 + threadIdx.x;   // grid exact: 4*NN threads
    int i = t >> 2;
    int sub = t & 3;
    int beg = row_start[i];
    int end = row_start[i + 1];
    float4 a0 = make_float4(0.f,0.f,0.f,0.f), a1 = a0, a2 = a0, a3 = a0;
    if (sub == 0) {
        float di = dinv[i];
        float sl = di * di;
        const float4* hp = reinterpret_cast<const float4*>(h1 + (size_t)i * HID);
        float4 v0 = hp[0], v1 = hp[1], v2 = hp[2], v3 = hp[3];
        a0 = make_float4(v0.x*sl, v0.y*sl, v0.z*sl, v0.w*sl);
        a1 = make_float4(v1.x*sl, v1.y*sl, v1.z*sl, v1.w*sl);
        a2 = make_float4(v2.x*sl, v2.y*sl, v2.z*sl, v2.w*sl);
        a3 = make_float4(v3.x*sl, v3.y*sl, v3.z*sl, v3.w*sl);
    }
    for (int p = beg + sub; p < end; p += 4) {
        int2 ev = edges[p];
        float nv = __int_as_float(ev.y);
        const float4* hp = reinterpret_cast<const float4*>(h1 + (size_t)ev.x * HID);
        float4 v0 = hp[0], v1 = hp[1], v2 = hp[2], v3 = hp[3];
        a0.x = fmaf(v0.x, nv, a0.x); a0.y = fmaf(v0.y, nv, a0.y);
        a0.z = fmaf(v0.z, nv, a0.z); a0.w = fmaf(v0.w, nv, a0.w);
        a1.x = fmaf(v1.x, nv, a1.x); a1.y = fmaf(v1.y, nv, a1.y);
        a1.z = fmaf(v1.z, nv, a1.z); a1.w = fmaf(v1.w, nv, a1.w);
        a2.x = fmaf(v2.x, nv, a2.x); a2.y = fmaf(v2.y, nv, a2.y);
        a2.z = fmaf(v2.z, nv, a2.z); a2.w = fmaf(v2.w, nv, a2.w);
        a3.x = fmaf(v3.x, nv, a3.x); a3.y = fmaf(v3.y, nv, a3.y);
        a3.z = fmaf(v3.z, nv, a3.z); a3.w = fmaf(v3.w, nv, a3.w);
    }
#pragma unroll
    for (int m = 1; m <= 2; m <<= 1) {
        a0.x += __shfl_xor(a0.x, m); a0.y += __shfl_xor(a0.y, m);
        a0.z += __shfl_xor(a0.z, m); a0.w += __shfl_xor(a0.w, m);
        a1.x += __shfl_xor(a1.x, m); a1.y += __shfl_xor(a1.y, m);
        a1.z += __shfl_xor(a1.z, m); a1.w += __shfl_xor(a1.w, m);
        a2.x += __shfl_xor(a2.x, m); a2.y += __shfl_xor(a2.y, m);
        a2.z += __shfl_xor(a2.z, m); a2.w += __shfl_xor(a2.w, m);
        a3.x += __shfl_xor(a3.x, m); a3.y += __shfl_xor(a3.y, m);
        a3.z += __shfl_xor(a3.z, m); a3.w += __shfl_xor(a3.w, m);
    }
    // all 4 lanes now hold the full 16-feature aggregation
    float av[HID] = { a0.x, a0.y, a0.z, a0.w, a1.x, a1.y, a1.z, a1.w,
                      a2.x, a2.y, a2.z, a2.w, a3.x, a3.y, a3.z, a3.w };
    // lane `sub` computes output columns [sub*10, sub*10+10)
    float* op = out + (size_t)i * NC + sub * 10;
#pragma unroll
    for (int c = 0; c < 10; ++c) {
        int col = sub * 10 + c;
        float s = sb2[col];
#pragma unroll
        for (int k = 0; k < HID; ++k)
            s = fmaf(av[k], sW2[k * NC + col], s);
        op[c] = s;
    }
}

// ---------------- launch ----------------

extern "C" void kernel_launch(void* const* d_in, const int* in_sizes, int n_in,
                              void* d_out, int out_size, void* d_ws, size_t ws_size,
                              hipStream_t stream) {
    const float* x  = (const float*)d_in[0];
    const int*   ei = (const int*)d_in[1];   // [2, E] int32
    const float* w  = (const float*)d_in[2];
    const float* W1 = (const float*)d_in[3];
    const float* b1 = (const float*)d_in[4];
    const float* W2 = (const float*)d_in[5];
    const float* b2 = (const float*)d_in[6];
    float* out = (float*)d_out;

    const int* src = ei;        // edge_index[0]
    const int* dst = ei + NE;   // edge_index[1]

    // workspace layout (4B elements)
    char* wsb = (char*)d_ws;
    float* dinv      = (float*)(wsb);                       // NN
    int*   cnt       = (int*)  (wsb + 200064LL * 4);        // NN
    int*   row_start = (int*)  (wsb + 400128LL * 4);        // NN+1
    int*   partial   = (int*)  (wsb + 600192LL * 4);        // 1024
    int2*  edges     = (int2*) (wsb + 601216LL * 4);        // NE int2 (8B each)
    float* h         = (float*)(wsb + 13401216LL * 4);      // NN*HID
    float* h1        = (float*)(wsb + 16601216LL * 4);      // NN*HID
    // total: 19801216 * 4B = 79.2 MB

    const int BN = (NN + 255) / 256;   // 782
    const int BE = (NE + 255) / 256;   // 25000
    const int BG = (4 * NN) / 256;     // 3125 (exact)

    k_init   <<<BN, 256, 0, stream>>>(dinv, cnt);
    k_hist   <<<BE, 256, 0, stream>>>(dst, w, dinv, cnt);
    k_dinv   <<<BN, 256, 0, stream>>>(dinv);
    k_scan1  <<<NBLK_SCAN, 256, 0, stream>>>(cnt, row_start, partial);
    k_scan2  <<<1, 1024, 0, stream>>>(partial);
    k_scan3  <<<BN, 256, 0, stream>>>(row_start, partial, cnt);
    k_scatter<<<BE, 256, 0, stream>>>(src, dst, w, dinv, row_start, cnt, edges);
    k_gemm1  <<<BN, 256, 0, stream>>>(x, W1, h);
    k_gather1<<<BG, 256, 0, stream>>>(row_start, edges, h, dinv, b1, h1);
    k_gather2<<<BG, 256, 0, stream>>>(row_start, edges, h1, dinv, W2, b2, out);
}

// Round 3
// 670.339 us; speedup vs baseline: 1.9343x; 1.8550x over previous
//
#include <hip/hip_runtime.h>

#define NN 200000
#define NE 6400000
#define FIN 256
#define HID 16
#define NC 40
#define NBKT 782        // ceil(NN/256) dst-buckets of 256 nodes
#define NCHUNK 196      // coarse chunks
#define EPC 32768       // edges per chunk (196*32768 >= NE)
#define STAGE_CAP 9472  // bucket stage capacity (mean 8192, sigma ~90 -> 14 sigma)

// ---- 1. per-chunk coarse histogram over 782 dst-buckets (LDS atomics only) ----
__global__ __launch_bounds__(256) void k_chist(const int* __restrict__ dst,
                                               int* __restrict__ hist_g) {
    __shared__ int sh[NBKT];
    int c = blockIdx.x;
    for (int j = threadIdx.x; j < NBKT; j += 256) sh[j] = 0;
    __syncthreads();
    int beg = c * EPC;
    int end = min(beg + EPC, NE);
    for (int e = beg + threadIdx.x; e < end; e += 256)
        atomicAdd(&sh[dst[e] >> 8], 1);
    __syncthreads();
    for (int j = threadIdx.x; j < NBKT; j += 256)
        hist_g[c * NBKT + j] = sh[j];
}

// ---- 2. bucket totals ----
__global__ __launch_bounds__(256) void k_btotal(const int* __restrict__ hist_g,
                                                int* __restrict__ totals) {
    int b = blockIdx.x * 256 + threadIdx.x;
    if (b < NBKT) {
        int s = 0;
#pragma unroll 8
        for (int c = 0; c < NCHUNK; ++c) s += hist_g[c * NBKT + b];
        totals[b] = s;
    }
}

// ---- 3. exclusive scan of 782 totals -> binBase ----
__global__ __launch_bounds__(1024) void k_bscan(const int* __restrict__ totals,
                                                int* __restrict__ binBase) {
    __shared__ int sm[1024];
    int t = threadIdx.x;
    int v = (t < NBKT) ? totals[t] : 0;
    sm[t] = v;
    __syncthreads();
    for (int off = 1; off < 1024; off <<= 1) {
        int x = (t >= off) ? sm[t - off] : 0;
        __syncthreads();
        sm[t] += x;
        __syncthreads();
    }
    if (t < NBKT) binBase[t] = sm[t] - v;
    if (t == 0) binBase[NBKT] = NE;
}

// ---- 4. per-bucket scan over chunks, in place: hist -> chunk cursor bases ----
__global__ __launch_bounds__(256) void k_cscan(int* __restrict__ hist_g,
                                               const int* __restrict__ binBase) {
    __shared__ int sm[256];
    int b = blockIdx.x, t = threadIdx.x;
    int v = (t < NCHUNK) ? hist_g[t * NBKT + b] : 0;
    sm[t] = v;
    __syncthreads();
    for (int off = 1; off < 256; off <<= 1) {
        int x = (t >= off) ? sm[t - off] : 0;
        __syncthreads();
        sm[t] += x;
        __syncthreads();
    }
    if (t < NCHUNK) hist_g[t * NBKT + b] = sm[t] - v + binBase[b];
}

// ---- 5. coarse scatter: edges grouped by dst-bucket; pack {src|dl<<18, w} ----
__global__ __launch_bounds__(256) void k_cscatter(const int* __restrict__ src,
                                                  const int* __restrict__ dst,
                                                  const float* __restrict__ w,
                                                  const int* __restrict__ coff,
                                                  int2* __restrict__ ebuf) {
    __shared__ int scur[NBKT];
    int c = blockIdx.x;
    for (int j = threadIdx.x; j < NBKT; j += 256) scur[j] = coff[c * NBKT + j];
    __syncthreads();
    int beg = c * EPC;
    int end = min(beg + EPC, NE);
    for (int e = beg + threadIdx.x; e < end; e += 256) {
        int d = dst[e];
        int pos = atomicAdd(&scur[d >> 8], 1);
        ebuf[pos] = make_int2(src[e] | ((d & 255) << 18), __float_as_int(w[e]));
    }
}

// ---- 6. per-bucket: fine counts + weighted degree (LDS) -> dinv, row_start ----
__global__ __launch_bounds__(256) void k_bucket(const int* __restrict__ binBase,
                                                const int2* __restrict__ ebuf,
                                                float* __restrict__ dinv,
                                                int* __restrict__ row_start) {
    __shared__ int scnt[256];
    __shared__ float sdeg[256];
    __shared__ int ssc[256];
    int b = blockIdx.x, t = threadIdx.x;
    scnt[t] = 0;
    sdeg[t] = 1.0f;  // self-loop weight
    __syncthreads();
    int beg = binBase[b], end = binBase[b + 1];
    for (int e = beg + t; e < end; e += 256) {
        int2 r = ebuf[e];
        int dl = (r.x >> 18) & 255;
        atomicAdd(&scnt[dl], 1);
        atomicAdd(&sdeg[dl], __int_as_float(r.y));
    }
    __syncthreads();
    int node = b * 256 + t;
    if (node < NN) dinv[node] = rsqrtf(sdeg[t]);  // deg >= 1 (self-loop)
    int v = scnt[t];
    ssc[t] = v;
    __syncthreads();
    for (int off = 1; off < 256; off <<= 1) {
        int x = (t >= off) ? ssc[t - off] : 0;
        __syncthreads();
        ssc[t] += x;
        __syncthreads();
    }
    if (node < NN) row_start[node] = beg + ssc[t] - v;
    if (b == NBKT - 1 && t == 0) row_start[NN] = NE;
}

// ---- 7. per-bucket in-place fine scatter; fuses norm = dinv[s]*w*dinv[d] ----
__global__ __launch_bounds__(256) void k_bscatter(const int* __restrict__ binBase,
                                                  const int* __restrict__ row_start,
                                                  const float* __restrict__ dinv,
                                                  int2* __restrict__ ebuf) {
    __shared__ int2 stage[STAGE_CAP];
    __shared__ int scur[256];
    __shared__ float sdv[256];
    int b = blockIdx.x, t = threadIdx.x;
    int beg = binBase[b], end = binBase[b + 1];
    int cnt = end - beg;
    for (int j = t; j < cnt; j += 256) stage[j] = ebuf[beg + j];
    int node = b * 256 + t;
    scur[t] = (node < NN) ? row_start[node] : 0;
    sdv[t] = (node < NN) ? dinv[node] : 0.0f;
    __syncthreads();
    for (int j = t; j < cnt; j += 256) {
        int2 r = stage[j];
        int s = r.x & 0x3FFFF;
        int dl = (r.x >> 18) & 255;
        float nv = dinv[s] * __int_as_float(r.y) * sdv[dl];
        int pos = atomicAdd(&scur[dl], 1);
        ebuf[pos] = make_int2(s, __float_as_int(nv));
    }
}

// ---- h = x @ W1 ----
__global__ __launch_bounds__(256) void k_gemm1(const float* __restrict__ x,
                                               const float* __restrict__ W1,
                                               float* __restrict__ h) {
    int row = blockIdx.x * 256 + threadIdx.x;
    if (row >= NN) return;
    float acc[HID];
#pragma unroll
    for (int f = 0; f < HID; ++f) acc[f] = 0.0f;
    const float4* x4 = reinterpret_cast<const float4*>(x + (size_t)row * FIN);
    for (int kk = 0; kk < FIN / 4; ++kk) {
        float4 xv = x4[kk];
#pragma unroll
        for (int j = 0; j < 4; ++j) {
            float xs = (j == 0) ? xv.x : (j == 1) ? xv.y : (j == 2) ? xv.z : xv.w;
            int k = kk * 4 + j;
#pragma unroll
            for (int f = 0; f < HID; ++f)
                acc[f] = fmaf(xs, W1[k * HID + f], acc[f]);
        }
    }
    float4* hp = reinterpret_cast<float4*>(h + (size_t)row * HID);
#pragma unroll
    for (int q = 0; q < HID / 4; ++q)
        hp[q] = make_float4(acc[q*4], acc[q*4+1], acc[q*4+2], acc[q*4+3]);
}

// ---- gather layer 1: h1 = relu(Ahat h + b1) ----
__global__ __launch_bounds__(256) void k_gather1(const int* __restrict__ row_start,
                                                 const int2* __restrict__ edges,
                                                 const float* __restrict__ h,
                                                 const float* __restrict__ dinv,
                                                 const float* __restrict__ b1,
                                                 float* __restrict__ h1) {
    int t = blockIdx.x * 256 + threadIdx.x;
    int i = t >> 2;
    int sub = t & 3;
    int beg = row_start[i];
    int end = row_start[i + 1];
    float4 a0 = make_float4(0.f,0.f,0.f,0.f), a1 = a0, a2 = a0, a3 = a0;
    if (sub == 0) {
        float di = dinv[i];
        float sl = di * di;
        const float4* hp = reinterpret_cast<const float4*>(h + (size_t)i * HID);
        float4 v0 = hp[0], v1 = hp[1], v2 = hp[2], v3 = hp[3];
        a0 = make_float4(v0.x*sl, v0.y*sl, v0.z*sl, v0.w*sl);
        a1 = make_float4(v1.x*sl, v1.y*sl, v1.z*sl, v1.w*sl);
        a2 = make_float4(v2.x*sl, v2.y*sl, v2.z*sl, v2.w*sl);
        a3 = make_float4(v3.x*sl, v3.y*sl, v3.z*sl, v3.w*sl);
    }
    for (int p = beg + sub; p < end; p += 4) {
        int2 ev = edges[p];
        float nv = __int_as_float(ev.y);
        const float4* hp = reinterpret_cast<const float4*>(h + (size_t)ev.x * HID);
        float4 v0 = hp[0], v1 = hp[1], v2 = hp[2], v3 = hp[3];
        a0.x = fmaf(v0.x, nv, a0.x); a0.y = fmaf(v0.y, nv, a0.y);
        a0.z = fmaf(v0.z, nv, a0.z); a0.w = fmaf(v0.w, nv, a0.w);
        a1.x = fmaf(v1.x, nv, a1.x); a1.y = fmaf(v1.y, nv, a1.y);
        a1.z = fmaf(v1.z, nv, a1.z); a1.w = fmaf(v1.w, nv, a1.w);
        a2.x = fmaf(v2.x, nv, a2.x); a2.y = fmaf(v2.y, nv, a2.y);
        a2.z = fmaf(v2.z, nv, a2.z); a2.w = fmaf(v2.w, nv, a2.w);
        a3.x = fmaf(v3.x, nv, a3.x); a3.y = fmaf(v3.y, nv, a3.y);
        a3.z = fmaf(v3.z, nv, a3.z); a3.w = fmaf(v3.w, nv, a3.w);
    }
#pragma unroll
    for (int m = 1; m <= 2; m <<= 1) {
        a0.x += __shfl_xor(a0.x, m); a0.y += __shfl_xor(a0.y, m);
        a0.z += __shfl_xor(a0.z, m); a0.w += __shfl_xor(a0.w, m);
        a1.x += __shfl_xor(a1.x, m); a1.y += __shfl_xor(a1.y, m);
        a1.z += __shfl_xor(a1.z, m); a1.w += __shfl_xor(a1.w, m);
        a2.x += __shfl_xor(a2.x, m); a2.y += __shfl_xor(a2.y, m);
        a2.z += __shfl_xor(a2.z, m); a2.w += __shfl_xor(a2.w, m);
        a3.x += __shfl_xor(a3.x, m); a3.y += __shfl_xor(a3.y, m);
        a3.z += __shfl_xor(a3.z, m); a3.w += __shfl_xor(a3.w, m);
    }
    float4 q = (sub == 0) ? a0 : (sub == 1) ? a1 : (sub == 2) ? a2 : a3;
    float4 bb = reinterpret_cast<const float4*>(b1)[sub];
    q.x = fmaxf(q.x + bb.x, 0.f);
    q.y = fmaxf(q.y + bb.y, 0.f);
    q.z = fmaxf(q.z + bb.z, 0.f);
    q.w = fmaxf(q.w + bb.w, 0.f);
    reinterpret_cast<float4*>(h1 + (size_t)i * HID)[sub] = q;
}

// ---- gather layer 2 fused with GEMM2: out = (Ahat h1) @ W2 + b2 ----
__global__ __launch_bounds__(256) void k_gather2(const int* __restrict__ row_start,
                                                 const int2* __restrict__ edges,
                                                 const float* __restrict__ h1,
                                                 const float* __restrict__ dinv,
                                                 const float* __restrict__ W2,
                                                 const float* __restrict__ b2,
                                                 float* __restrict__ out) {
    __shared__ float sW2[HID * NC];
    __shared__ float sb2[NC];
    {
        int tt = threadIdx.x;
        for (int j = tt; j < HID * NC; j += 256) sW2[j] = W2[j];
        if (tt < NC) sb2[tt] = b2[tt];
    }
    __syncthreads();
    int t = blockIdx.x * 256 + threadIdx.x;
    int i = t >> 2;
    int sub = t & 3;
    int beg = row_start[i];
    int end = row_start[i + 1];
    float4 a0 = make_float4(0.f,0.f,0.f,0.f), a1 = a0, a2 = a0, a3 = a0;
    if (sub == 0) {
        float di = dinv[i];
        float sl = di * di;
        const float4* hp = reinterpret_cast<const float4*>(h1 + (size_t)i * HID);
        float4 v0 = hp[0], v1 = hp[1], v2 = hp[2], v3 = hp[3];
        a0 = make_float4(v0.x*sl, v0.y*sl, v0.z*sl, v0.w*sl);
        a1 = make_float4(v1.x*sl, v1.y*sl, v1.z*sl, v1.w*sl);
        a2 = make_float4(v2.x*sl, v2.y*sl, v2.z*sl, v2.w*sl);
        a3 = make_float4(v3.x*sl, v3.y*sl, v3.z*sl, v3.w*sl);
    }
    for (int p = beg + sub; p < end; p += 4) {
        int2 ev = edges[p];
        float nv = __int_as_float(ev.y);
        const float4* hp = reinterpret_cast<const float4*>(h1 + (size_t)ev.x * HID);
        float4 v0 = hp[0], v1 = hp[1], v2 = hp[2], v3 = hp[3];
        a0.x = fmaf(v0.x, nv, a0.x); a0.y = fmaf(v0.y, nv, a0.y);
        a0.z = fmaf(v0.z, nv, a0.z); a0.w = fmaf(v0.w, nv, a0.w);
        a1.x = fmaf(v1.x, nv, a1.x); a1.y = fmaf(v1.y, nv, a1.y);
        a1.z = fmaf(v1.z, nv, a1.z); a1.w = fmaf(v1.w, nv, a1.w);
        a2.x = fmaf(v2.x, nv, a2.x); a2.y = fmaf(v2.y, nv, a2.y);
        a2.z = fmaf(v2.z, nv, a2.z); a2.w = fmaf(v2.w, nv, a2.w);
        a3.x = fmaf(v3.x, nv, a3.x); a3.y = fmaf(v3.y, nv, a3.y);
        a3.z = fmaf(v3.z, nv, a3.z); a3.w = fmaf(v3.w, nv, a3.w);
    }
#pragma unroll
    for (int m = 1; m <= 2; m <<= 1) {
        a0.x += __shfl_xor(a0.x, m); a0.y += __shfl_xor(a0.y, m);
        a0.z += __shfl_xor(a0.z, m); a0.w += __shfl_xor(a0.w, m);
        a1.x += __shfl_xor(a1.x, m); a1.y += __shfl_xor(a1.y, m);
        a1.z += __shfl_xor(a1.z, m); a1.w += __shfl_xor(a1.w, m);
        a2.x += __shfl_xor(a2.x, m); a2.y += __shfl_xor(a2.y, m);
        a2.z += __shfl_xor(a2.z, m); a2.w += __shfl_xor(a2.w, m);
        a3.x += __shfl_xor(a3.x, m); a3.y += __shfl_xor(a3.y, m);
        a3.z += __shfl_xor(a3.z, m); a3.w += __shfl_xor(a3.w, m);
    }
    float av[HID] = { a0.x, a0.y, a0.z, a0.w, a1.x, a1.y, a1.z, a1.w,
                      a2.x, a2.y, a2.z, a2.w, a3.x, a3.y, a3.z, a3.w };
    float* op = out + (size_t)i * NC + sub * 10;
#pragma unroll
    for (int c = 0; c < 10; ++c) {
        int col = sub * 10 + c;
        float s = sb2[col];
#pragma unroll
        for (int k = 0; k < HID; ++k)
            s = fmaf(av[k], sW2[k * NC + col], s);
        op[c] = s;
    }
}

// ---- launch ----
extern "C" void kernel_launch(void* const* d_in, const int* in_sizes, int n_in,
                              void* d_out, int out_size, void* d_ws, size_t ws_size,
                              hipStream_t stream) {
    const float* x  = (const float*)d_in[0];
    const int*   ei = (const int*)d_in[1];
    const float* w  = (const float*)d_in[2];
    const float* W1 = (const float*)d_in[3];
    const float* b1 = (const float*)d_in[4];
    const float* W2 = (const float*)d_in[5];
    const float* b2 = (const float*)d_in[6];
    float* out = (float*)d_out;

    const int* src = ei;
    const int* dst = ei + NE;

    // workspace layout (4B words): total 19,755,520 words = 79.0 MB
    char* wsb = (char*)d_ws;
    float* dinv      = (float*)(wsb);                      // 200064
    int*   row_start = (int*)  (wsb + 200064LL * 4);       // 200064 (NN+1 used)
    int*   totals    = (int*)  (wsb + 400128LL * 4);       // 1024
    int*   binBase   = (int*)  (wsb + 401152LL * 4);       // 1024 (NBKT+1 used)
    int*   hist_g    = (int*)  (wsb + 402176LL * 4);       // 196*782 = 153272 (pad 153344)
    int2*  ebuf      = (int2*) (wsb + 555520LL * 4);       // NE int2 = 12.8M words
    float* h         = (float*)(wsb + 13355520LL * 4);     // NN*HID
    float* h1        = (float*)(wsb + 16555520LL * 4);     // NN*HID

    const int BN = (NN + 255) / 256;   // 782
    const int BG = (4 * NN) / 256;     // 3125

    k_chist   <<<NCHUNK, 256, 0, stream>>>(dst, hist_g);
    k_btotal  <<<(NBKT + 255) / 256, 256, 0, stream>>>(hist_g, totals);
    k_bscan   <<<1, 1024, 0, stream>>>(totals, binBase);
    k_cscan   <<<NBKT, 256, 0, stream>>>(hist_g, binBase);
    k_cscatter<<<NCHUNK, 256, 0, stream>>>(src, dst, w, hist_g, ebuf);
    k_bucket  <<<NBKT, 256, 0, stream>>>(binBase, ebuf, dinv, row_start);
    k_bscatter<<<NBKT, 256, 0, stream>>>(binBase, row_start, dinv, ebuf);
    k_gemm1   <<<BN, 256, 0, stream>>>(x, W1, h);
    k_gather1 <<<BG, 256, 0, stream>>>(row_start, ebuf, h, dinv, b1, h1);
    k_gather2 <<<BG, 256, 0, stream>>>(row_start, ebuf, h1, dinv, W2, b2, out);
}

// Round 4
// 634.227 us; speedup vs baseline: 2.0444x; 1.0569x over previous
//
#include <hip/hip_runtime.h>

#define NN 200000
#define NE 6400000
#define FIN 256
#define HID 16
#define NC 40
#define NBKT 782        // ceil(NN/256) dst-buckets of 256 nodes
#define NCHUNK 2048     // coarse chunks (8 blocks/CU)
#define EPC 3125        // edges per chunk: 2048*3125 = 6.4M exact
#define CPT 8           // chunks per thread in btotal/cscan (2048/256)
#define STAGE_CAP 9472  // bucket stage capacity (mean 8192, ~14 sigma)

// ---- 1. per-chunk coarse histogram over 782 dst-buckets (LDS atomics only) ----
__global__ __launch_bounds__(256) void k_chist(const int* __restrict__ dst,
                                               int* __restrict__ hist_g) {
    __shared__ int sh[NBKT];
    int c = blockIdx.x;
    for (int j = threadIdx.x; j < NBKT; j += 256) sh[j] = 0;
    __syncthreads();
    int beg = c * EPC;
    int end = min(beg + EPC, NE);
    for (int e = beg + threadIdx.x; e < end; e += 256)
        atomicAdd(&sh[dst[e] >> 8], 1);
    __syncthreads();
    for (int j = threadIdx.x; j < NBKT; j += 256)
        hist_g[c * NBKT + j] = sh[j];
}

// ---- 2. bucket totals: block per bucket, tree reduce over 2048 chunks ----
__global__ __launch_bounds__(256) void k_btotal(const int* __restrict__ hist_g,
                                                int* __restrict__ totals) {
    __shared__ int sm[256];
    int b = blockIdx.x, t = threadIdx.x;
    int s = 0;
#pragma unroll
    for (int j = 0; j < CPT; ++j)
        s += hist_g[(t * CPT + j) * NBKT + b];
    sm[t] = s;
    __syncthreads();
    for (int off = 128; off > 0; off >>= 1) {
        if (t < off) sm[t] += sm[t + off];
        __syncthreads();
    }
    if (t == 0) totals[b] = sm[0];
}

// ---- 3. exclusive scan of 782 totals -> binBase ----
__global__ __launch_bounds__(1024) void k_bscan(const int* __restrict__ totals,
                                                int* __restrict__ binBase) {
    __shared__ int sm[1024];
    int t = threadIdx.x;
    int v = (t < NBKT) ? totals[t] : 0;
    sm[t] = v;
    __syncthreads();
    for (int off = 1; off < 1024; off <<= 1) {
        int x = (t >= off) ? sm[t - off] : 0;
        __syncthreads();
        sm[t] += x;
        __syncthreads();
    }
    if (t < NBKT) binBase[t] = sm[t] - v;
    if (t == 0) binBase[NBKT] = NE;
}

// ---- 4. per-bucket scan over 2048 chunks, in place: hist -> chunk cursor bases ----
__global__ __launch_bounds__(256) void k_cscan(int* __restrict__ hist_g,
                                               const int* __restrict__ binBase) {
    __shared__ int sm[256];
    int b = blockIdx.x, t = threadIdx.x;
    int loc[CPT];
    int s = 0;
#pragma unroll
    for (int j = 0; j < CPT; ++j) {
        loc[j] = hist_g[(t * CPT + j) * NBKT + b];
        s += loc[j];
    }
    sm[t] = s;
    __syncthreads();
    for (int off = 1; off < 256; off <<= 1) {
        int x = (t >= off) ? sm[t - off] : 0;
        __syncthreads();
        sm[t] += x;
        __syncthreads();
    }
    int base = binBase[b] + sm[t] - s;   // exclusive prefix for this thread's slab
#pragma unroll
    for (int j = 0; j < CPT; ++j) {
        hist_g[(t * CPT + j) * NBKT + b] = base;
        base += loc[j];
    }
}

// ---- 5. coarse scatter: edges grouped by dst-bucket; pack {src|dl<<18, w} ----
__global__ __launch_bounds__(256) void k_cscatter(const int* __restrict__ src,
                                                  const int* __restrict__ dst,
                                                  const float* __restrict__ w,
                                                  const int* __restrict__ coff,
                                                  int2* __restrict__ ebuf) {
    __shared__ int scur[NBKT];
    int c = blockIdx.x;
    for (int j = threadIdx.x; j < NBKT; j += 256) scur[j] = coff[c * NBKT + j];
    __syncthreads();
    int beg = c * EPC;
    int end = min(beg + EPC, NE);
    for (int e = beg + threadIdx.x; e < end; e += 256) {
        int d = dst[e];
        int pos = atomicAdd(&scur[d >> 8], 1);
        ebuf[pos] = make_int2(src[e] | ((d & 255) << 18), __float_as_int(w[e]));
    }
}

// ---- 6. per-bucket: fine counts + weighted degree (LDS) -> dinv, row_start ----
__global__ __launch_bounds__(256) void k_bucket(const int* __restrict__ binBase,
                                                const int2* __restrict__ ebuf,
                                                float* __restrict__ dinv,
                                                int* __restrict__ row_start) {
    __shared__ int scnt[256];
    __shared__ float sdeg[256];
    __shared__ int ssc[256];
    int b = blockIdx.x, t = threadIdx.x;
    scnt[t] = 0;
    sdeg[t] = 1.0f;  // self-loop weight
    __syncthreads();
    int beg = binBase[b], end = binBase[b + 1];
    for (int e = beg + t; e < end; e += 256) {
        int2 r = ebuf[e];
        int dl = (r.x >> 18) & 255;
        atomicAdd(&scnt[dl], 1);
        atomicAdd(&sdeg[dl], __int_as_float(r.y));
    }
    __syncthreads();
    int node = b * 256 + t;
    if (node < NN) dinv[node] = rsqrtf(sdeg[t]);  // deg >= 1 (self-loop)
    int v = scnt[t];
    ssc[t] = v;
    __syncthreads();
    for (int off = 1; off < 256; off <<= 1) {
        int x = (t >= off) ? ssc[t - off] : 0;
        __syncthreads();
        ssc[t] += x;
        __syncthreads();
    }
    if (node < NN) row_start[node] = beg + ssc[t] - v;
    if (b == NBKT - 1 && t == 0) row_start[NN] = NE;
}

// ---- 7. per-bucket in-place fine scatter; fuses norm = dinv[s]*w*dinv[d] ----
__global__ __launch_bounds__(256) void k_bscatter(const int* __restrict__ binBase,
                                                  const int* __restrict__ row_start,
                                                  const float* __restrict__ dinv,
                                                  int2* __restrict__ ebuf) {
    __shared__ int2 stage[STAGE_CAP];
    __shared__ int scur[256];
    __shared__ float sdv[256];
    int b = blockIdx.x, t = threadIdx.x;
    int beg = binBase[b], end = binBase[b + 1];
    int cnt = end - beg;
    for (int j = t; j < cnt; j += 256) stage[j] = ebuf[beg + j];
    int node = b * 256 + t;
    scur[t] = (node < NN) ? row_start[node] : 0;
    sdv[t] = (node < NN) ? dinv[node] : 0.0f;
    __syncthreads();
    for (int j = t; j < cnt; j += 256) {
        int2 r = stage[j];
        int s = r.x & 0x3FFFF;
        int dl = (r.x >> 18) & 255;
        float nv = dinv[s] * __int_as_float(r.y) * sdv[dl];
        int pos = atomicAdd(&scur[dl], 1);
        ebuf[pos] = make_int2(s, __float_as_int(nv));
    }
}

// ---- h = x @ W1 ----
__global__ __launch_bounds__(256) void k_gemm1(const float* __restrict__ x,
                                               const float* __restrict__ W1,
                                               float* __restrict__ h) {
    int row = blockIdx.x * 256 + threadIdx.x;
    if (row >= NN) return;
    float acc[HID];
#pragma unroll
    for (int f = 0; f < HID; ++f) acc[f] = 0.0f;
    const float4* x4 = reinterpret_cast<const float4*>(x + (size_t)row * FIN);
    for (int kk = 0; kk < FIN / 4; ++kk) {
        float4 xv = x4[kk];
#pragma unroll
        for (int j = 0; j < 4; ++j) {
            float xs = (j == 0) ? xv.x : (j == 1) ? xv.y : (j == 2) ? xv.z : xv.w;
            int k = kk * 4 + j;
#pragma unroll
            for (int f = 0; f < HID; ++f)
                acc[f] = fmaf(xs, W1[k * HID + f], acc[f]);
        }
    }
    float4* hp = reinterpret_cast<float4*>(h + (size_t)row * HID);
#pragma unroll
    for (int q = 0; q < HID / 4; ++q)
        hp[q] = make_float4(acc[q*4], acc[q*4+1], acc[q*4+2], acc[q*4+3]);
}

// ---- gather layer 1: h1 = relu(Ahat h + b1) ----
__global__ __launch_bounds__(256) void k_gather1(const int* __restrict__ row_start,
                                                 const int2* __restrict__ edges,
                                                 const float* __restrict__ h,
                                                 const float* __restrict__ dinv,
                                                 const float* __restrict__ b1,
                                                 float* __restrict__ h1) {
    int t = blockIdx.x * 256 + threadIdx.x;
    int i = t >> 2;
    int sub = t & 3;
    int beg = row_start[i];
    int end = row_start[i + 1];
    float4 a0 = make_float4(0.f,0.f,0.f,0.f), a1 = a0, a2 = a0, a3 = a0;
    if (sub == 0) {
        float di = dinv[i];
        float sl = di * di;
        const float4* hp = reinterpret_cast<const float4*>(h + (size_t)i * HID);
        float4 v0 = hp[0], v1 = hp[1], v2 = hp[2], v3 = hp[3];
        a0 = make_float4(v0.x*sl, v0.y*sl, v0.z*sl, v0.w*sl);
        a1 = make_float4(v1.x*sl, v1.y*sl, v1.z*sl, v1.w*sl);
        a2 = make_float4(v2.x*sl, v2.y*sl, v2.z*sl, v2.w*sl);
        a3 = make_float4(v3.x*sl, v3.y*sl, v3.z*sl, v3.w*sl);
    }
    for (int p = beg + sub; p < end; p += 4) {
        int2 ev = edges[p];
        float nv = __int_as_float(ev.y);
        const float4* hp = reinterpret_cast<const float4*>(h + (size_t)ev.x * HID);
        float4 v0 = hp[0], v1 = hp[1], v2 = hp[2], v3 = hp[3];
        a0.x = fmaf(v0.x, nv, a0.x); a0.y = fmaf(v0.y, nv, a0.y);
        a0.z = fmaf(v0.z, nv, a0.z); a0.w = fmaf(v0.w, nv, a0.w);
        a1.x = fmaf(v1.x, nv, a1.x); a1.y = fmaf(v1.y, nv, a1.y);
        a1.z = fmaf(v1.z, nv, a1.z); a1.w = fmaf(v1.w, nv, a1.w);
        a2.x = fmaf(v2.x, nv, a2.x); a2.y = fmaf(v2.y, nv, a2.y);
        a2.z = fmaf(v2.z, nv, a2.z); a2.w = fmaf(v2.w, nv, a2.w);
        a3.x = fmaf(v3.x, nv, a3.x); a3.y = fmaf(v3.y, nv, a3.y);
        a3.z = fmaf(v3.z, nv, a3.z); a3.w = fmaf(v3.w, nv, a3.w);
    }
#pragma unroll
    for (int m = 1; m <= 2; m <<= 1) {
        a0.x += __shfl_xor(a0.x, m); a0.y += __shfl_xor(a0.y, m);
        a0.z += __shfl_xor(a0.z, m); a0.w += __shfl_xor(a0.w, m);
        a1.x += __shfl_xor(a1.x, m); a1.y += __shfl_xor(a1.y, m);
        a1.z += __shfl_xor(a1.z, m); a1.w += __shfl_xor(a1.w, m);
        a2.x += __shfl_xor(a2.x, m); a2.y += __shfl_xor(a2.y, m);
        a2.z += __shfl_xor(a2.z, m); a2.w += __shfl_xor(a2.w, m);
        a3.x += __shfl_xor(a3.x, m); a3.y += __shfl_xor(a3.y, m);
        a3.z += __shfl_xor(a3.z, m); a3.w += __shfl_xor(a3.w, m);
    }
    float4 q = (sub == 0) ? a0 : (sub == 1) ? a1 : (sub == 2) ? a2 : a3;
    float4 bb = reinterpret_cast<const float4*>(b1)[sub];
    q.x = fmaxf(q.x + bb.x, 0.f);
    q.y = fmaxf(q.y + bb.y, 0.f);
    q.z = fmaxf(q.z + bb.z, 0.f);
    q.w = fmaxf(q.w + bb.w, 0.f);
    reinterpret_cast<float4*>(h1 + (size_t)i * HID)[sub] = q;
}

// ---- gather layer 2 fused with GEMM2: out = (Ahat h1) @ W2 + b2 ----
__global__ __launch_bounds__(256) void k_gather2(const int* __restrict__ row_start,
                                                 const int2* __restrict__ edges,
                                                 const float* __restrict__ h1,
                                                 const float* __restrict__ dinv,
                                                 const float* __restrict__ W2,
                                                 const float* __restrict__ b2,
                                                 float* __restrict__ out) {
    __shared__ float sW2[HID * NC];
    __shared__ float sb2[NC];
    {
        int tt = threadIdx.x;
        for (int j = tt; j < HID * NC; j += 256) sW2[j] = W2[j];
        if (tt < NC) sb2[tt] = b2[tt];
    }
    __syncthreads();
    int t = blockIdx.x * 256 + threadIdx.x;
    int i = t >> 2;
    int sub = t & 3;
    int beg = row_start[i];
    int end = row_start[i + 1];
    float4 a0 = make_float4(0.f,0.f,0.f,0.f), a1 = a0, a2 = a0, a3 = a0;
    if (sub == 0) {
        float di = dinv[i];
        float sl = di * di;
        const float4* hp = reinterpret_cast<const float4*>(h1 + (size_t)i * HID);
        float4 v0 = hp[0], v1 = hp[1], v2 = hp[2], v3 = hp[3];
        a0 = make_float4(v0.x*sl, v0.y*sl, v0.z*sl, v0.w*sl);
        a1 = make_float4(v1.x*sl, v1.y*sl, v1.z*sl, v1.w*sl);
        a2 = make_float4(v2.x*sl, v2.y*sl, v2.z*sl, v2.w*sl);
        a3 = make_float4(v3.x*sl, v3.y*sl, v3.z*sl, v3.w*sl);
    }
    for (int p = beg + sub; p < end; p += 4) {
        int2 ev = edges[p];
        float nv = __int_as_float(ev.y);
        const float4* hp = reinterpret_cast<const float4*>(h1 + (size_t)ev.x * HID);
        float4 v0 = hp[0], v1 = hp[1], v2 = hp[2], v3 = hp[3];
        a0.x = fmaf(v0.x, nv, a0.x); a0.y = fmaf(v0.y, nv, a0.y);
        a0.z = fmaf(v0.z, nv, a0.z); a0.w = fmaf(v0.w, nv, a0.w);
        a1.x = fmaf(v1.x, nv, a1.x); a1.y = fmaf(v1.y, nv, a1.y);
        a1.z = fmaf(v1.z, nv, a1.z); a1.w = fmaf(v1.w, nv, a1.w);
        a2.x = fmaf(v2.x, nv, a2.x); a2.y = fmaf(v2.y, nv, a2.y);
        a2.z = fmaf(v2.z, nv, a2.z); a2.w = fmaf(v2.w, nv, a2.w);
        a3.x = fmaf(v3.x, nv, a3.x); a3.y = fmaf(v3.y, nv, a3.y);
        a3.z = fmaf(v3.z, nv, a3.z); a3.w = fmaf(v3.w, nv, a3.w);
    }
#pragma unroll
    for (int m = 1; m <= 2; m <<= 1) {
        a0.x += __shfl_xor(a0.x, m); a0.y += __shfl_xor(a0.y, m);
        a0.z += __shfl_xor(a0.z, m); a0.w += __shfl_xor(a0.w, m);
        a1.x += __shfl_xor(a1.x, m); a1.y += __shfl_xor(a1.y, m);
        a1.z += __shfl_xor(a1.z, m); a1.w += __shfl_xor(a1.w, m);
        a2.x += __shfl_xor(a2.x, m); a2.y += __shfl_xor(a2.y, m);
        a2.z += __shfl_xor(a2.z, m); a2.w += __shfl_xor(a2.w, m);
        a3.x += __shfl_xor(a3.x, m); a3.y += __shfl_xor(a3.y, m);
        a3.z += __shfl_xor(a3.z, m); a3.w += __shfl_xor(a3.w, m);
    }
    float av[HID] = { a0.x, a0.y, a0.z, a0.w, a1.x, a1.y, a1.z, a1.w,
                      a2.x, a2.y, a2.z, a2.w, a3.x, a3.y, a3.z, a3.w };
    float* op = out + (size_t)i * NC + sub * 10;
#pragma unroll
    for (int c = 0; c < 10; ++c) {
        int col = sub * 10 + c;
        float s = sb2[col];
#pragma unroll
        for (int k = 0; k < HID; ++k)
            s = fmaf(av[k], sW2[k * NC + col], s);
        op[c] = s;
    }
}

// ---- launch ----
extern "C" void kernel_launch(void* const* d_in, const int* in_sizes, int n_in,
                              void* d_out, int out_size, void* d_ws, size_t ws_size,
                              hipStream_t stream) {
    const float* x  = (const float*)d_in[0];
    const int*   ei = (const int*)d_in[1];
    const float* w  = (const float*)d_in[2];
    const float* W1 = (const float*)d_in[3];
    const float* b1 = (const float*)d_in[4];
    const float* W2 = (const float*)d_in[5];
    const float* b2 = (const float*)d_in[6];
    float* out = (float*)d_out;

    const int* src = ei;
    const int* dst = ei + NE;

    // workspace layout (4B words), total 19.6M words = 78.4 MB.
    // hist_g (2048*782 = 1,601,536 words) is ALIASED into the h region:
    // hist_g is dead after k_cscatter; h is first written by k_gemm1 (later).
    char* wsb = (char*)d_ws;
    float* dinv      = (float*)(wsb);                      // 200064
    int*   row_start = (int*)  (wsb + 200064LL * 4);       // 200064 (NN+1 used)
    int*   totals    = (int*)  (wsb + 400128LL * 4);       // 1024
    int*   binBase   = (int*)  (wsb + 401152LL * 4);       // 1024 (NBKT+1 used)
    int2*  ebuf      = (int2*) (wsb + 402176LL * 4);       // NE int2 = 12.8M words
    float* h         = (float*)(wsb + 13202176LL * 4);     // NN*HID (3.2M words)
    int*   hist_g    = (int*)  (wsb + 13202176LL * 4);     // aliases h (1.6M <= 3.2M)
    float* h1        = (float*)(wsb + 16402176LL * 4);     // NN*HID

    const int BN = (NN + 255) / 256;   // 782
    const int BG = (4 * NN) / 256;     // 3125

    k_chist   <<<NCHUNK, 256, 0, stream>>>(dst, hist_g);
    k_btotal  <<<NBKT, 256, 0, stream>>>(hist_g, totals);
    k_bscan   <<<1, 1024, 0, stream>>>(totals, binBase);
    k_cscan   <<<NBKT, 256, 0, stream>>>(hist_g, binBase);
    k_cscatter<<<NCHUNK, 256, 0, stream>>>(src, dst, w, hist_g, ebuf);
    k_bucket  <<<NBKT, 256, 0, stream>>>(binBase, ebuf, dinv, row_start);
    k_bscatter<<<NBKT, 256, 0, stream>>>(binBase, row_start, dinv, ebuf);
    k_gemm1   <<<BN, 256, 0, stream>>>(x, W1, h);
    k_gather1 <<<BG, 256, 0, stream>>>(row_start, ebuf, h, dinv, b1, h1);
    k_gather2 <<<BG, 256, 0, stream>>>(row_start, ebuf, h1, dinv, W2, b2, out);
}

// Round 5
// 592.832 us; speedup vs baseline: 2.1872x; 1.0698x over previous
//
#include <hip/hip_runtime.h>

#define NN 200000
#define NE 6400000
#define FIN 256
#define HID 16
#define NC 40
#define NBKT 782        // ceil(NN/256) dst-buckets of 256 nodes
#define NCHUNK 2048     // histogram microchunks
#define EPC 3125        // edges per microchunk: 2048*3125 = 6.4M exact
#define CPT 8           // chunks per thread in btotal/cscan (2048/256)
#define SC_BLOCKS 256   // scatter blocks
#define SC_THREADS 512
#define MC_PER_BLK 8    // microchunks per scatter block (25000 edges -> runs of ~32/bucket)
#define STAGE_CAP 9472  // bucket stage capacity (mean 8192, ~14 sigma)

// ---- 1. per-microchunk coarse histogram over 782 dst-buckets (LDS atomics only) ----
__global__ __launch_bounds__(256) void k_chist(const int* __restrict__ dst,
                                               int* __restrict__ hist_g) {
    __shared__ int sh[NBKT];
    int c = blockIdx.x;
    for (int j = threadIdx.x; j < NBKT; j += 256) sh[j] = 0;
    __syncthreads();
    int beg = c * EPC;
    int end = min(beg + EPC, NE);
    for (int e = beg + threadIdx.x; e < end; e += 256)
        atomicAdd(&sh[dst[e] >> 8], 1);
    __syncthreads();
    for (int j = threadIdx.x; j < NBKT; j += 256)
        hist_g[c * NBKT + j] = sh[j];
}

// ---- 2. bucket totals: block per bucket, tree reduce over 2048 chunks ----
__global__ __launch_bounds__(256) void k_btotal(const int* __restrict__ hist_g,
                                                int* __restrict__ totals) {
    __shared__ int sm[256];
    int b = blockIdx.x, t = threadIdx.x;
    int s = 0;
#pragma unroll
    for (int j = 0; j < CPT; ++j)
        s += hist_g[(t * CPT + j) * NBKT + b];
    sm[t] = s;
    __syncthreads();
    for (int off = 128; off > 0; off >>= 1) {
        if (t < off) sm[t] += sm[t + off];
        __syncthreads();
    }
    if (t == 0) totals[b] = sm[0];
}

// ---- 3. exclusive scan of 782 totals -> binBase ----
__global__ __launch_bounds__(1024) void k_bscan(const int* __restrict__ totals,
                                                int* __restrict__ binBase) {
    __shared__ int sm[1024];
    int t = threadIdx.x;
    int v = (t < NBKT) ? totals[t] : 0;
    sm[t] = v;
    __syncthreads();
    for (int off = 1; off < 1024; off <<= 1) {
        int x = (t >= off) ? sm[t - off] : 0;
        __syncthreads();
        sm[t] += x;
        __syncthreads();
    }
    if (t < NBKT) binBase[t] = sm[t] - v;
    if (t == 0) binBase[NBKT] = NE;
}

// ---- 4. per-bucket scan over 2048 microchunks, in place: hist -> cursor bases ----
__global__ __launch_bounds__(256) void k_cscan(int* __restrict__ hist_g,
                                               const int* __restrict__ binBase) {
    __shared__ int sm[256];
    int b = blockIdx.x, t = threadIdx.x;
    int loc[CPT];
    int s = 0;
#pragma unroll
    for (int j = 0; j < CPT; ++j) {
        loc[j] = hist_g[(t * CPT + j) * NBKT + b];
        s += loc[j];
    }
    sm[t] = s;
    __syncthreads();
    for (int off = 1; off < 256; off <<= 1) {
        int x = (t >= off) ? sm[t - off] : 0;
        __syncthreads();
        sm[t] += x;
        __syncthreads();
    }
    int base = binBase[b] + sm[t] - s;   // exclusive prefix for this thread's slab
#pragma unroll
    for (int j = 0; j < CPT; ++j) {
        hist_g[(t * CPT + j) * NBKT + b] = base;
        base += loc[j];
    }
}

// ---- 5. coarse scatter: 8 consecutive microchunks per block -> long per-bucket runs.
// Cursor seed = microchunk 8c's base; pooled range == union of the 8 ranges (scan is
// cumulative in chunk order), so positions remain disjoint and in-bucket.
__global__ __launch_bounds__(512) void k_cscatter(const int* __restrict__ src,
                                                  const int* __restrict__ dst,
                                                  const float* __restrict__ w,
                                                  const int* __restrict__ coff,
                                                  int2* __restrict__ ebuf) {
    __shared__ int scur[NBKT];
    int c = blockIdx.x;
    int mc0 = c * MC_PER_BLK;
    for (int j = threadIdx.x; j < NBKT; j += SC_THREADS)
        scur[j] = coff[mc0 * NBKT + j];
    __syncthreads();
    int beg = mc0 * EPC;
    int end = min(beg + MC_PER_BLK * EPC, NE);
    for (int e = beg + threadIdx.x; e < end; e += SC_THREADS) {
        int d = dst[e];
        int pos = atomicAdd(&scur[d >> 8], 1);
        ebuf[pos] = make_int2(src[e] | ((d & 255) << 18), __float_as_int(w[e]));
    }
}

// ---- 6. per-bucket: fine counts + weighted degree (LDS) -> dinv, row_start ----
__global__ __launch_bounds__(256) void k_bucket(const int* __restrict__ binBase,
                                                const int2* __restrict__ ebuf,
                                                float* __restrict__ dinv,
                                                int* __restrict__ row_start) {
    __shared__ int scnt[256];
    __shared__ float sdeg[256];
    __shared__ int ssc[256];
    int b = blockIdx.x, t = threadIdx.x;
    scnt[t] = 0;
    sdeg[t] = 1.0f;  // self-loop weight
    __syncthreads();
    int beg = binBase[b], end = binBase[b + 1];
    for (int e = beg + t; e < end; e += 256) {
        int2 r = ebuf[e];
        int dl = (r.x >> 18) & 255;
        atomicAdd(&scnt[dl], 1);
        atomicAdd(&sdeg[dl], __int_as_float(r.y));
    }
    __syncthreads();
    int node = b * 256 + t;
    if (node < NN) dinv[node] = rsqrtf(sdeg[t]);  // deg >= 1 (self-loop)
    int v = scnt[t];
    ssc[t] = v;
    __syncthreads();
    for (int off = 1; off < 256; off <<= 1) {
        int x = (t >= off) ? ssc[t - off] : 0;
        __syncthreads();
        ssc[t] += x;
        __syncthreads();
    }
    if (node < NN) row_start[node] = beg + ssc[t] - v;
    if (b == NBKT - 1 && t == 0) row_start[NN] = NE;
}

// ---- 7. per-bucket in-place fine scatter; fuses norm = dinv[s]*w*dinv[d] ----
__global__ __launch_bounds__(256) void k_bscatter(const int* __restrict__ binBase,
                                                  const int* __restrict__ row_start,
                                                  const float* __restrict__ dinv,
                                                  int2* __restrict__ ebuf) {
    __shared__ int2 stage[STAGE_CAP];
    __shared__ int scur[256];
    __shared__ float sdv[256];
    int b = blockIdx.x, t = threadIdx.x;
    int beg = binBase[b], end = binBase[b + 1];
    int cnt = end - beg;
    for (int j = t; j < cnt; j += 256) stage[j] = ebuf[beg + j];
    int node = b * 256 + t;
    scur[t] = (node < NN) ? row_start[node] : 0;
    sdv[t] = (node < NN) ? dinv[node] : 0.0f;
    __syncthreads();
    for (int j = t; j < cnt; j += 256) {
        int2 r = stage[j];
        int s = r.x & 0x3FFFF;
        int dl = (r.x >> 18) & 255;
        float nv = dinv[s] * __int_as_float(r.y) * sdv[dl];
        int pos = atomicAdd(&scur[dl], 1);
        ebuf[pos] = make_int2(s, __float_as_int(nv));
    }
}

// ---- h = x @ W1 ----
__global__ __launch_bounds__(256) void k_gemm1(const float* __restrict__ x,
                                               const float* __restrict__ W1,
                                               float* __restrict__ h) {
    int row = blockIdx.x * 256 + threadIdx.x;
    if (row >= NN) return;
    float acc[HID];
#pragma unroll
    for (int f = 0; f < HID; ++f) acc[f] = 0.0f;
    const float4* x4 = reinterpret_cast<const float4*>(x + (size_t)row * FIN);
    for (int kk = 0; kk < FIN / 4; ++kk) {
        float4 xv = x4[kk];
#pragma unroll
        for (int j = 0; j < 4; ++j) {
            float xs = (j == 0) ? xv.x : (j == 1) ? xv.y : (j == 2) ? xv.z : xv.w;
            int k = kk * 4 + j;
#pragma unroll
            for (int f = 0; f < HID; ++f)
                acc[f] = fmaf(xs, W1[k * HID + f], acc[f]);
        }
    }
    float4* hp = reinterpret_cast<float4*>(h + (size_t)row * HID);
#pragma unroll
    for (int q = 0; q < HID / 4; ++q)
        hp[q] = make_float4(acc[q*4], acc[q*4+1], acc[q*4+2], acc[q*4+3]);
}

// ---- gather layer 1: h1 = relu(Ahat h + b1) ----
__global__ __launch_bounds__(256) void k_gather1(const int* __restrict__ row_start,
                                                 const int2* __restrict__ edges,
                                                 const float* __restrict__ h,
                                                 const float* __restrict__ dinv,
                                                 const float* __restrict__ b1,
                                                 float* __restrict__ h1) {
    int t = blockIdx.x * 256 + threadIdx.x;
    int i = t >> 2;
    int sub = t & 3;
    int beg = row_start[i];
    int end = row_start[i + 1];
    float4 a0 = make_float4(0.f,0.f,0.f,0.f), a1 = a0, a2 = a0, a3 = a0;
    if (sub == 0) {
        float di = dinv[i];
        float sl = di * di;
        const float4* hp = reinterpret_cast<const float4*>(h + (size_t)i * HID);
        float4 v0 = hp[0], v1 = hp[1], v2 = hp[2], v3 = hp[3];
        a0 = make_float4(v0.x*sl, v0.y*sl, v0.z*sl, v0.w*sl);
        a1 = make_float4(v1.x*sl, v1.y*sl, v1.z*sl, v1.w*sl);
        a2 = make_float4(v2.x*sl, v2.y*sl, v2.z*sl, v2.w*sl);
        a3 = make_float4(v3.x*sl, v3.y*sl, v3.z*sl, v3.w*sl);
    }
    for (int p = beg + sub; p < end; p += 4) {
        int2 ev = edges[p];
        float nv = __int_as_float(ev.y);
        const float4* hp = reinterpret_cast<const float4*>(h + (size_t)ev.x * HID);
        float4 v0 = hp[0], v1 = hp[1], v2 = hp[2], v3 = hp[3];
        a0.x = fmaf(v0.x, nv, a0.x); a0.y = fmaf(v0.y, nv, a0.y);
        a0.z = fmaf(v0.z, nv, a0.z); a0.w = fmaf(v0.w, nv, a0.w);
        a1.x = fmaf(v1.x, nv, a1.x); a1.y = fmaf(v1.y, nv, a1.y);
        a1.z = fmaf(v1.z, nv, a1.z); a1.w = fmaf(v1.w, nv, a1.w);
        a2.x = fmaf(v2.x, nv, a2.x); a2.y = fmaf(v2.y, nv, a2.y);
        a2.z = fmaf(v2.z, nv, a2.z); a2.w = fmaf(v2.w, nv, a2.w);
        a3.x = fmaf(v3.x, nv, a3.x); a3.y = fmaf(v3.y, nv, a3.y);
        a3.z = fmaf(v3.z, nv, a3.z); a3.w = fmaf(v3.w, nv, a3.w);
    }
#pragma unroll
    for (int m = 1; m <= 2; m <<= 1) {
        a0.x += __shfl_xor(a0.x, m); a0.y += __shfl_xor(a0.y, m);
        a0.z += __shfl_xor(a0.z, m); a0.w += __shfl_xor(a0.w, m);
        a1.x += __shfl_xor(a1.x, m); a1.y += __shfl_xor(a1.y, m);
        a1.z += __shfl_xor(a1.z, m); a1.w += __shfl_xor(a1.w, m);
        a2.x += __shfl_xor(a2.x, m); a2.y += __shfl_xor(a2.y, m);
        a2.z += __shfl_xor(a2.z, m); a2.w += __shfl_xor(a2.w, m);
        a3.x += __shfl_xor(a3.x, m); a3.y += __shfl_xor(a3.y, m);
        a3.z += __shfl_xor(a3.z, m); a3.w += __shfl_xor(a3.w, m);
    }
    float4 q = (sub == 0) ? a0 : (sub == 1) ? a1 : (sub == 2) ? a2 : a3;
    float4 bb = reinterpret_cast<const float4*>(b1)[sub];
    q.x = fmaxf(q.x + bb.x, 0.f);
    q.y = fmaxf(q.y + bb.y, 0.f);
    q.z = fmaxf(q.z + bb.z, 0.f);
    q.w = fmaxf(q.w + bb.w, 0.f);
    reinterpret_cast<float4*>(h1 + (size_t)i * HID)[sub] = q;
}

// ---- gather layer 2 fused with GEMM2: out = (Ahat h1) @ W2 + b2 ----
__global__ __launch_bounds__(256) void k_gather2(const int* __restrict__ row_start,
                                                 const int2* __restrict__ edges,
                                                 const float* __restrict__ h1,
                                                 const float* __restrict__ dinv,
                                                 const float* __restrict__ W2,
                                                 const float* __restrict__ b2,
                                                 float* __restrict__ out) {
    __shared__ float sW2[HID * NC];
    __shared__ float sb2[NC];
    {
        int tt = threadIdx.x;
        for (int j = tt; j < HID * NC; j += 256) sW2[j] = W2[j];
        if (tt < NC) sb2[tt] = b2[tt];
    }
    __syncthreads();
    int t = blockIdx.x * 256 + threadIdx.x;
    int i = t >> 2;
    int sub = t & 3;
    int beg = row_start[i];
    int end = row_start[i + 1];
    float4 a0 = make_float4(0.f,0.f,0.f,0.f), a1 = a0, a2 = a0, a3 = a0;
    if (sub == 0) {
        float di = dinv[i];
        float sl = di * di;
        const float4* hp = reinterpret_cast<const float4*>(h1 + (size_t)i * HID);
        float4 v0 = hp[0], v1 = hp[1], v2 = hp[2], v3 = hp[3];
        a0 = make_float4(v0.x*sl, v0.y*sl, v0.z*sl, v0.w*sl);
        a1 = make_float4(v1.x*sl, v1.y*sl, v1.z*sl, v1.w*sl);
        a2 = make_float4(v2.x*sl, v2.y*sl, v2.z*sl, v2.w*sl);
        a3 = make_float4(v3.x*sl, v3.y*sl, v3.z*sl, v3.w*sl);
    }
    for (int p = beg + sub; p < end; p += 4) {
        int2 ev = edges[p];
        float nv = __int_as_float(ev.y);
        const float4* hp = reinterpret_cast<const float4*>(h1 + (size_t)ev.x * HID);
        float4 v0 = hp[0], v1 = hp[1], v2 = hp[2], v3 = hp[3];
        a0.x = fmaf(v0.x, nv, a0.x); a0.y = fmaf(v0.y, nv, a0.y);
        a0.z = fmaf(v0.z, nv, a0.z); a0.w = fmaf(v0.w, nv, a0.w);
        a1.x = fmaf(v1.x, nv, a1.x); a1.y = fmaf(v1.y, nv, a1.y);
        a1.z = fmaf(v1.z, nv, a1.z); a1.w = fmaf(v1.w, nv, a1.w);
        a2.x = fmaf(v2.x, nv, a2.x); a2.y = fmaf(v2.y, nv, a2.y);
        a2.z = fmaf(v2.z, nv, a2.z); a2.w = fmaf(v2.w, nv, a2.w);
        a3.x = fmaf(v3.x, nv, a3.x); a3.y = fmaf(v3.y, nv, a3.y);
        a3.z = fmaf(v3.z, nv, a3.z); a3.w = fmaf(v3.w, nv, a3.w);
    }
#pragma unroll
    for (int m = 1; m <= 2; m <<= 1) {
        a0.x += __shfl_xor(a0.x, m); a0.y += __shfl_xor(a0.y, m);
        a0.z += __shfl_xor(a0.z, m); a0.w += __shfl_xor(a0.w, m);
        a1.x += __shfl_xor(a1.x, m); a1.y += __shfl_xor(a1.y, m);
        a1.z += __shfl_xor(a1.z, m); a1.w += __shfl_xor(a1.w, m);
        a2.x += __shfl_xor(a2.x, m); a2.y += __shfl_xor(a2.y, m);
        a2.z += __shfl_xor(a2.z, m); a2.w += __shfl_xor(a2.w, m);
        a3.x += __shfl_xor(a3.x, m); a3.y += __shfl_xor(a3.y, m);
        a3.z += __shfl_xor(a3.z, m); a3.w += __shfl_xor(a3.w, m);
    }
    float av[HID] = { a0.x, a0.y, a0.z, a0.w, a1.x, a1.y, a1.z, a1.w,
                      a2.x, a2.y, a2.z, a2.w, a3.x, a3.y, a3.z, a3.w };
    float* op = out + (size_t)i * NC + sub * 10;
#pragma unroll
    for (int c = 0; c < 10; ++c) {
        int col = sub * 10 + c;
        float s = sb2[col];
#pragma unroll
        for (int k = 0; k < HID; ++k)
            s = fmaf(av[k], sW2[k * NC + col], s);
        op[c] = s;
    }
}

// ---- launch ----
extern "C" void kernel_launch(void* const* d_in, const int* in_sizes, int n_in,
                              void* d_out, int out_size, void* d_ws, size_t ws_size,
                              hipStream_t stream) {
    const float* x  = (const float*)d_in[0];
    const int*   ei = (const int*)d_in[1];
    const float* w  = (const float*)d_in[2];
    const float* W1 = (const float*)d_in[3];
    const float* b1 = (const float*)d_in[4];
    const float* W2 = (const float*)d_in[5];
    const float* b2 = (const float*)d_in[6];
    float* out = (float*)d_out;

    const int* src = ei;
    const int* dst = ei + NE;

    // workspace layout (4B words), total 19.6M words = 78.4 MB.
    // hist_g (2048*782 = 1,601,536 words) ALIASED into h region (dead after cscatter).
    char* wsb = (char*)d_ws;
    float* dinv      = (float*)(wsb);                      // 200064
    int*   row_start = (int*)  (wsb + 200064LL * 4);       // 200064 (NN+1 used)
    int*   totals    = (int*)  (wsb + 400128LL * 4);       // 1024
    int*   binBase   = (int*)  (wsb + 401152LL * 4);       // 1024 (NBKT+1 used)
    int2*  ebuf      = (int2*) (wsb + 402176LL * 4);       // NE int2 = 12.8M words
    float* h         = (float*)(wsb + 13202176LL * 4);     // NN*HID (3.2M words)
    int*   hist_g    = (int*)  (wsb + 13202176LL * 4);     // aliases h (1.6M <= 3.2M)
    float* h1        = (float*)(wsb + 16402176LL * 4);     // NN*HID

    const int BN = (NN + 255) / 256;   // 782
    const int BG = (4 * NN) / 256;     // 3125

    k_chist   <<<NCHUNK, 256, 0, stream>>>(dst, hist_g);
    k_btotal  <<<NBKT, 256, 0, stream>>>(hist_g, totals);
    k_bscan   <<<1, 1024, 0, stream>>>(totals, binBase);
    k_cscan   <<<NBKT, 256, 0, stream>>>(hist_g, binBase);
    k_cscatter<<<SC_BLOCKS, SC_THREADS, 0, stream>>>(src, dst, w, hist_g, ebuf);
    k_bucket  <<<NBKT, 256, 0, stream>>>(binBase, ebuf, dinv, row_start);
    k_bscatter<<<NBKT, 256, 0, stream>>>(binBase, row_start, dinv, ebuf);
    k_gemm1   <<<BN, 256, 0, stream>>>(x, W1, h);
    k_gather1 <<<BG, 256, 0, stream>>>(row_start, ebuf, h, dinv, b1, h1);
    k_gather2 <<<BG, 256, 0, stream>>>(row_start, ebuf, h1, dinv, W2, b2, out);
}